// Round 2
// baseline (146.893 us; speedup 1.0000x reference)
//
#include <hip/hip_runtime.h>

#define C_IN 128
#define C_OUT 64
#define SPLIT 32768   // rows >= SPLIT wrap negative in the int32 sort key

// One tiny block: w_sum[c] = sum_o W[c,o]; init S := E; detect edge-buffer layout.
__global__ void k_init(const float* __restrict__ W, float* __restrict__ w_sum,
                       const int* __restrict__ ei, int* __restrict__ pS,
                       int* __restrict__ pStride, int E) {
    int c = threadIdx.x;
    if (c < C_IN) {
        float s = 0.f;
        #pragma unroll
        for (int o = 0; o < C_OUT; ++o) s += W[c * C_OUT + o];
        w_sum[c] = s;
    }
    if (c == 0) {
        pS[0] = E;  // default: no row >= SPLIT
        // int64 layout => flat int32 view is [lo,hi,lo,hi,...] with hi==0.
        // int32 layout => odd slots are col values; for row==0 edges col!=0 always.
        int z = (ei[1] == 0) && (ei[3] == 0) && (ei[5] == 0) && (ei[7] == 0);
        pStride[0] = z ? 4 : 2;
    }
}

// cnt histogram of rows + detect the wrap split point S (rows are sorted).
__global__ void k_hist(const int* __restrict__ ei, const int* __restrict__ pStride,
                       int* __restrict__ cnt, int* __restrict__ pS, int E) {
    int e = blockIdx.x * blockDim.x + threadIdx.x;
    if (e >= E) return;
    int st = pStride[0];
    int r = ei[st * e];
    atomicAdd(cnt + r, 1);
    if (r >= SPLIT && (e == 0 || ei[st * (e - 1)] < SPLIT)) pS[0] = e;
}

// t[i] = 2 * (x[i] . w_sum) / (cnt[i] + 1 + 1e-16)   (+1 = self loop)
__global__ void k_t(const float* __restrict__ x, const float* __restrict__ w_sum,
                    const int* __restrict__ cnt, float* __restrict__ t, int N) {
    __shared__ float ws[C_IN];
    if (threadIdx.x < C_IN) ws[threadIdx.x] = w_sum[threadIdx.x];
    __syncthreads();
    int gid = blockIdx.x * blockDim.x + threadIdx.x;
    int node = gid >> 2;   // 4 lanes per node
    int sub  = gid & 3;
    if (node < N) {
        const float4* xr = (const float4*)(x + (size_t)node * C_IN);
        float s = 0.f;
        #pragma unroll
        for (int j = 0; j < 8; ++j) {
            float4 v = xr[sub + 4 * j];
            const float* wp = ws + (sub + 4 * j) * 4;
            s += v.x * wp[0] + v.y * wp[1] + v.z * wp[2] + v.w * wp[3];
        }
        s += __shfl_xor(s, 1);
        s += __shfl_xor(s, 2);
        if (sub == 0) {
            float z = (float)(cnt[node] + 1) + 1e-16f;
            t[node] = 2.0f * s / z;
        }
    }
}

// lk[j] = s-value of permuted edge j  (perm = rotation by S):
//   orig = (S + j) mod E ;  lk[j] = t[row[orig]] / ed[orig]
__global__ void k_lookup(const int* __restrict__ ei, const int* __restrict__ pStride,
                         const int* __restrict__ pS, const float* __restrict__ ed,
                         const float* __restrict__ t, float* __restrict__ lk,
                         int N, int E) {
    int j = blockIdx.x * blockDim.x + threadIdx.x;
    if (j >= N) return;
    int S = pS[0], st = pStride[0];
    int orig = S + j; if (orig >= E) orig -= E;
    lk[j] = t[ei[st * orig]] / ed[orig];
}

// out[k] = lk[row[orig(k)]] - lk[col[orig(k)]],  orig(k) = (k+S) mod E; tail zeros.
__global__ void k_out(const int* __restrict__ ei, const int* __restrict__ pStride,
                      const int* __restrict__ pS, const float* __restrict__ lk,
                      float* __restrict__ out, int E, int N) {
    int k = blockIdx.x * blockDim.x + threadIdx.x;
    if (k < E) {
        int S = pS[0], st = pStride[0];
        int orig = k + S; if (orig >= E) orig -= E;
        int r = ei[st * orig];
        int c = ei[st * orig + (st >> 1)];
        out[k] = lk[r] - lk[c];
    } else if (k < E + N) {
        out[k] = 0.0f;
    }
}

extern "C" void kernel_launch(void* const* d_in, const int* in_sizes, int n_in,
                              void* d_out, int out_size, void* d_ws, size_t ws_size,
                              hipStream_t stream) {
    const float* x  = (const float*)d_in[0];
    const int*   ei = (const int*)d_in[1];
    const float* ed = (const float*)d_in[2];
    const float* W  = (const float*)d_in[3];
    // d_in[4] (attention) cancels out of the math entirely (softmax of equal
    // logits within every segment) and does not affect the output.
    float* out = (float*)d_out;

    int N = in_sizes[0] / C_IN;   // 65536
    int E = in_sizes[2];          // 1048576

    char* ws = (char*)d_ws;
    int*   cnt     = (int*)ws;                          // N ints
    float* t       = (float*)(ws + (size_t)N * 4);      // N floats
    float* lk      = (float*)(ws + (size_t)N * 8);      // N floats
    float* w_sum   = (float*)(ws + (size_t)N * 12);     // 128 floats
    int*   pS      = (int*)(ws + (size_t)N * 12 + 512); // 1 int
    int*   pStride = pS + 1;                            // 1 int

    hipMemsetAsync(cnt, 0, (size_t)N * 4, stream);
    k_init<<<1, 128, 0, stream>>>(W, w_sum, ei, pS, pStride, E);
    k_hist<<<(E + 255) / 256, 256, 0, stream>>>(ei, pStride, cnt, pS, E);
    k_t<<<(N * 4 + 255) / 256, 256, 0, stream>>>(x, w_sum, cnt, t, N);
    k_lookup<<<(N + 255) / 256, 256, 0, stream>>>(ei, pStride, pS, ed, t, lk, N, E);
    k_out<<<(E + N + 255) / 256, 256, 0, stream>>>(ei, pStride, pS, lk, out, E, N);
}

// Round 3
// 103.100 us; speedup vs baseline: 1.4248x; 1.4248x over previous
//
#include <hip/hip_runtime.h>

#define C_IN 128
#define C_OUT 64
#define SPLIT 32768   // rows >= SPLIT wrap negative in the reference's int32 sort key

// One tiny block: w_sum[c] = sum_o W[c,o]; default S := E; detect edge-buffer layout.
__global__ void k_init(const float* __restrict__ W, float* __restrict__ w_sum,
                       const int* __restrict__ ei, int* __restrict__ pS,
                       int* __restrict__ pStride, int E) {
    int c = threadIdx.x;
    if (c < C_IN) {
        float s = 0.f;
        #pragma unroll
        for (int o = 0; o < C_OUT; ++o) s += W[c * C_OUT + o];
        w_sum[c] = s;
    }
    if (c == 0) {
        pS[0] = E;  // default: no row >= SPLIT
        // int64 layout => flat int32 view is [lo,hi,lo,hi,...] with hi==0 (ids < 2^16).
        // int32 layout => odd slots are col values; row==0 edges always have col!=0.
        int z = (ei[1] == 0) && (ei[3] == 0) && (ei[5] == 0) && (ei[7] == 0);
        pStride[0] = z ? 4 : 2;
    }
}

// Rows are sorted: each node's edges are one contiguous run.
// Run-boundary detection -> start[]/end[] plain stores, zero atomics.
// Also finds S = first e with row[e] >= SPLIT (the int32-wrap rotation point).
__global__ void k_bound(const int* __restrict__ ei, const int* __restrict__ pStride,
                        int* __restrict__ start, int* __restrict__ end,
                        int* __restrict__ pS, int E) {
    int e = blockIdx.x * blockDim.x + threadIdx.x;
    if (e >= E) return;
    int st = pStride[0];
    int r = ei[st * e];
    if (e == 0) {
        start[r] = 0;
        if (r >= SPLIT) pS[0] = 0;
    } else {
        int rp = ei[st * (e - 1)];
        if (r != rp) {
            end[rp] = e;
            start[r] = e;
            if (r >= SPLIT && rp < SPLIT) pS[0] = e;
        }
    }
    if (e == E - 1) end[r] = E;
}

// t[i] = 2 * (x[i] . w_sum) / (cnt[i] + 1 + 1e-16)   (+1 = self loop)
__global__ void k_t(const float* __restrict__ x, const float* __restrict__ w_sum,
                    const int* __restrict__ start, const int* __restrict__ end,
                    float* __restrict__ t, int N) {
    __shared__ float ws[C_IN];
    if (threadIdx.x < C_IN) ws[threadIdx.x] = w_sum[threadIdx.x];
    __syncthreads();
    int gid = blockIdx.x * blockDim.x + threadIdx.x;
    int node = gid >> 2;   // 4 lanes per node -> float4-coalesced x reads
    int sub  = gid & 3;
    if (node < N) {
        const float4* xr = (const float4*)(x + (size_t)node * C_IN);
        float s = 0.f;
        #pragma unroll
        for (int j = 0; j < 8; ++j) {
            float4 v = xr[sub + 4 * j];
            const float* wp = ws + (sub + 4 * j) * 4;
            s += v.x * wp[0] + v.y * wp[1] + v.z * wp[2] + v.w * wp[3];
        }
        s += __shfl_xor(s, 1);
        s += __shfl_xor(s, 2);
        if (sub == 0) {
            float z = (float)(end[node] - start[node] + 1) + 1e-16f;
            t[node] = 2.0f * s / z;
        }
    }
}

// lk[j] = s-value of permuted edge j  (perm = rotation by S):
//   orig = (S + j) mod E ;  lk[j] = t[row[orig]] / ed[orig]
__global__ void k_lookup(const int* __restrict__ ei, const int* __restrict__ pStride,
                         const int* __restrict__ pS, const float* __restrict__ ed,
                         const float* __restrict__ t, float* __restrict__ lk,
                         int N, int E) {
    int j = blockIdx.x * blockDim.x + threadIdx.x;
    if (j >= N) return;
    int S = pS[0], st = pStride[0];
    int orig = S + j; if (orig >= E) orig -= E;
    lk[j] = t[ei[st * orig]] / ed[orig];
}

// out[k] = lk[row[orig(k)]] - lk[col[orig(k)]],  orig(k) = (k+S) mod E; tail zeros.
__global__ void k_out(const int* __restrict__ ei, const int* __restrict__ pStride,
                      const int* __restrict__ pS, const float* __restrict__ lk,
                      float* __restrict__ out, int E, int N) {
    int k = blockIdx.x * blockDim.x + threadIdx.x;
    if (k < E) {
        int S = pS[0], st = pStride[0];
        int orig = k + S; if (orig >= E) orig -= E;
        int r = ei[st * orig];
        int c = ei[st * orig + (st >> 1)];
        out[k] = lk[r] - lk[c];
    } else if (k < E + N) {
        out[k] = 0.0f;
    }
}

extern "C" void kernel_launch(void* const* d_in, const int* in_sizes, int n_in,
                              void* d_out, int out_size, void* d_ws, size_t ws_size,
                              hipStream_t stream) {
    const float* x  = (const float*)d_in[0];
    const int*   ei = (const int*)d_in[1];
    const float* ed = (const float*)d_in[2];
    const float* W  = (const float*)d_in[3];
    // d_in[4] (attention) cancels out of the math entirely (softmax of equal
    // logits within every segment) and does not affect the output.
    float* out = (float*)d_out;

    int N = in_sizes[0] / C_IN;   // 65536
    int E = in_sizes[2];          // 1048576

    char* ws = (char*)d_ws;
    int*   start   = (int*)ws;                          // N ints
    int*   end     = start + N;                         // N ints
    float* t       = (float*)(ws + (size_t)N * 8);      // N floats
    float* lk      = (float*)(ws + (size_t)N * 12);     // N floats
    float* w_sum   = (float*)(ws + (size_t)N * 16);     // 128 floats
    int*   pS      = (int*)(ws + (size_t)N * 16 + 512); // 1 int
    int*   pStride = pS + 1;                            // 1 int

    hipMemsetAsync(start, 0, (size_t)N * 8, stream);    // start + end
    k_init<<<1, 128, 0, stream>>>(W, w_sum, ei, pS, pStride, E);
    k_bound<<<(E + 255) / 256, 256, 0, stream>>>(ei, pStride, start, end, pS, E);
    k_t<<<(N * 4 + 255) / 256, 256, 0, stream>>>(x, w_sum, start, end, t, N);
    k_lookup<<<(N + 255) / 256, 256, 0, stream>>>(ei, pStride, pS, ed, t, lk, N, E);
    k_out<<<(E + N + 255) / 256, 256, 0, stream>>>(ei, pStride, pS, lk, out, E, N);
}

// Round 4
// 98.906 us; speedup vs baseline: 1.4852x; 1.0424x over previous
//
#include <hip/hip_runtime.h>

#define C_IN 128
#define C_OUT 64
#define SPLIT 32768   // rows >= SPLIT wrap negative in the reference's int32 sort key

// Edge buffer layout probe (uniform, scalar, cache-hit):
// int64 layout => flat int32 view is [lo,hi,lo,hi,...] with hi==0 (ids < 2^16).
// int32 layout => odd slots are col values; row==0 edges always have col != 0.
__device__ __forceinline__ int probe_stride(const int* __restrict__ ei) {
    return ((ei[1] == 0) & (ei[3] == 0) & (ei[5] == 0) & (ei[7] == 0)) ? 4 : 2;
}

// Rows are sorted: each node's edges are one contiguous run.
// Boundary detection -> start[]/end[] plain stores, zero atomics, zero init
// (start/end of edge-less nodes are never read downstream: t[i] is consumed
// only via lk[j] = t[row[orig]] and row[orig] always has >=1 edge).
// Also: S = first e with row[e] >= SPLIT (int32-wrap rotation point; E if none),
// and block 0 computes w_sum[c] = sum_o W[c,o] (consumed by the NEXT kernel).
__global__ void k_bound(const int* __restrict__ ei, const float* __restrict__ W,
                        float* __restrict__ w_sum, int* __restrict__ start,
                        int* __restrict__ end, int* __restrict__ pS, int E) {
    int tid = threadIdx.x;
    if (blockIdx.x == 0 && tid < C_IN) {
        float s = 0.f;
        #pragma unroll
        for (int o = 0; o < C_OUT; ++o) s += W[tid * C_OUT + o];
        w_sum[tid] = s;
    }
    int e = blockIdx.x * blockDim.x + tid;
    if (e >= E) return;
    int st = probe_stride(ei);
    int r = ei[st * e];
    if (e == 0) {
        start[r] = 0;
        if (r >= SPLIT) pS[0] = 0;
    } else {
        int rp = ei[st * (e - 1)];
        if (r != rp) {
            end[rp] = e;
            start[r] = e;
            if (r >= SPLIT && rp < SPLIT) pS[0] = e;
        }
    }
    if (e == E - 1) {
        end[r] = E;
        if (r < SPLIT) pS[0] = E;   // no wrap anywhere -> identity permutation
    }
}

// t[i] = 2 * (x[i] . w_sum) / (cnt[i] + 1 + 1e-16)   (+1 = self loop)
__global__ void k_t(const float* __restrict__ x, const float* __restrict__ w_sum,
                    const int* __restrict__ start, const int* __restrict__ end,
                    float* __restrict__ t, int N) {
    __shared__ float ws[C_IN];
    if (threadIdx.x < C_IN) ws[threadIdx.x] = w_sum[threadIdx.x];
    __syncthreads();
    int gid = blockIdx.x * blockDim.x + threadIdx.x;
    int node = gid >> 2;   // 4 lanes per node -> float4-coalesced x reads
    int sub  = gid & 3;
    if (node < N) {
        const float4* xr = (const float4*)(x + (size_t)node * C_IN);
        float s = 0.f;
        #pragma unroll
        for (int j = 0; j < 8; ++j) {
            float4 v = xr[sub + 4 * j];
            const float* wp = ws + (sub + 4 * j) * 4;
            s += v.x * wp[0] + v.y * wp[1] + v.z * wp[2] + v.w * wp[3];
        }
        s += __shfl_xor(s, 1);
        s += __shfl_xor(s, 2);
        if (sub == 0) {
            float z = (float)(end[node] - start[node] + 1) + 1e-16f;
            t[node] = 2.0f * s / z;
        }
    }
}

// lk[j] = s-value of permuted edge j  (perm = rotation by S):
//   orig = (S + j) mod E ;  lk[j] = t[row[orig]] / ed[orig]
__global__ void k_lookup(const int* __restrict__ ei, const int* __restrict__ pS,
                         const float* __restrict__ ed, const float* __restrict__ t,
                         float* __restrict__ lk, int N, int E) {
    int j = blockIdx.x * blockDim.x + threadIdx.x;
    if (j >= N) return;
    int S = pS[0], st = probe_stride(ei);
    int orig = S + j; if (orig >= E) orig -= E;
    lk[j] = t[ei[st * orig]] / ed[orig];
}

// out[k] = lk[row[orig(k)]] - lk[col[orig(k)]],  orig(k) = (k+S) mod E; tail zeros.
__global__ void k_out(const int* __restrict__ ei, const int* __restrict__ pS,
                      const float* __restrict__ lk, float* __restrict__ out,
                      int E, int N) {
    int k = blockIdx.x * blockDim.x + threadIdx.x;
    if (k < E) {
        int S = pS[0], st = probe_stride(ei);
        int orig = k + S; if (orig >= E) orig -= E;
        int r = ei[st * orig];
        int c = ei[st * orig + (st >> 1)];
        out[k] = lk[r] - lk[c];
    } else if (k < E + N) {
        out[k] = 0.0f;
    }
}

extern "C" void kernel_launch(void* const* d_in, const int* in_sizes, int n_in,
                              void* d_out, int out_size, void* d_ws, size_t ws_size,
                              hipStream_t stream) {
    const float* x  = (const float*)d_in[0];
    const int*   ei = (const int*)d_in[1];
    const float* ed = (const float*)d_in[2];
    const float* W  = (const float*)d_in[3];
    // d_in[4] (attention) cancels out of the math entirely (softmax of equal
    // logits within every segment) and does not affect the output.
    float* out = (float*)d_out;

    int N = in_sizes[0] / C_IN;   // 65536
    int E = in_sizes[2];          // 1048576

    char* ws = (char*)d_ws;
    int*   start = (int*)ws;                           // N ints
    int*   end   = start + N;                          // N ints
    float* t     = (float*)(ws + (size_t)N * 8);       // N floats
    float* lk    = (float*)(ws + (size_t)N * 12);      // N floats
    float* w_sum = (float*)(ws + (size_t)N * 16);      // 128 floats
    int*   pS    = (int*)(ws + (size_t)N * 16 + 512);  // 1 int

    k_bound<<<(E + 255) / 256, 256, 0, stream>>>(ei, W, w_sum, start, end, pS, E);
    k_t<<<(N * 4 + 255) / 256, 256, 0, stream>>>(x, w_sum, start, end, t, N);
    k_lookup<<<(N + 255) / 256, 256, 0, stream>>>(ei, pS, ed, t, lk, N, E);
    k_out<<<(E + N + 255) / 256, 256, 0, stream>>>(ei, pS, lk, out, E, N);
}

// Round 5
// 95.885 us; speedup vs baseline: 1.5320x; 1.0315x over previous
//
#include <hip/hip_runtime.h>

#define C_IN 128
#define C_OUT 64
#define SPLIT 32768   // rows >= SPLIT wrap negative in the reference's int32 sort key

// Edge buffer layout probe (uniform, scalar, cache-hit):
// int64 layout => flat int32 view is [lo,hi,lo,hi,...] with hi==0 (ids < 2^16).
// int32 layout => odd slots are col values; row==0 edges always have col != 0.
__device__ __forceinline__ int probe_stride(const int* __restrict__ ei) {
    return ((ei[1] == 0) & (ei[3] == 0) & (ei[5] == 0) & (ei[7] == 0)) ? 4 : 2;
}

// Rows are sorted: each node's edges are one contiguous run.
// Boundary detection -> start[]/end[] plain stores, zero atomics, zero init
// (start/end of edge-less nodes stay poisoned; k_t rejects invalid runs and
// t of edge-less nodes is never consumed downstream).
// Also: S = first e with row[e] >= SPLIT (int32-wrap rotation point; E if none),
// and block 0 computes w_sum[c] = sum_o W[c,o] (consumed by the NEXT kernel).
__global__ void k_bound(const int* __restrict__ ei, const float* __restrict__ W,
                        float* __restrict__ w_sum, int* __restrict__ start,
                        int* __restrict__ end, int* __restrict__ pS, int E) {
    int tid = threadIdx.x;
    if (blockIdx.x == 0 && tid < C_IN) {
        float s = 0.f;
        #pragma unroll
        for (int o = 0; o < C_OUT; ++o) s += W[tid * C_OUT + o];
        w_sum[tid] = s;
    }
    int e = blockIdx.x * blockDim.x + tid;
    if (e >= E) return;
    int st = probe_stride(ei);
    int r = ei[st * e];
    if (e == 0) {
        start[r] = 0;
        if (r >= SPLIT) pS[0] = 0;
    } else {
        int rp = ei[st * (e - 1)];
        if (r != rp) {
            end[rp] = e;
            start[r] = e;
            if (r >= SPLIT && rp < SPLIT) pS[0] = e;
        }
    }
    if (e == E - 1) {
        end[r] = E;
        if (r < SPLIT) pS[0] = E;   // no wrap anywhere -> identity permutation
    }
}

// Per node i with edge run [b,en):
//   t = 2 * (x[i] . w_sum) / (en - b + 1 + 1e-16)        (+1 = self loop)
//   for each edge e in the run with j = (e - S mod E) < N:  lk[j] = t / ed[e]
// (lk[j] = s-value of permuted edge j; perm = rotation by S. Every j's node is
//  non-empty by construction, so all N lk entries get written here.)
__global__ void k_t(const float* __restrict__ x, const float* __restrict__ w_sum,
                    const int* __restrict__ start, const int* __restrict__ end,
                    const float* __restrict__ ed, const int* __restrict__ pS,
                    float* __restrict__ t, float* __restrict__ lk, int N, int E) {
    __shared__ float ws[C_IN];
    if (threadIdx.x < C_IN) ws[threadIdx.x] = w_sum[threadIdx.x];
    __syncthreads();
    int gid = blockIdx.x * blockDim.x + threadIdx.x;
    int node = gid >> 2;   // 4 lanes per node -> float4-coalesced x reads
    int sub  = gid & 3;
    if (node >= N) return;
    const float4* xr = (const float4*)(x + (size_t)node * C_IN);
    float s = 0.f;
    #pragma unroll
    for (int j = 0; j < 8; ++j) {
        float4 v = xr[sub + 4 * j];
        const float* wp = ws + (sub + 4 * j) * 4;
        s += v.x * wp[0] + v.y * wp[1] + v.z * wp[2] + v.w * wp[3];
    }
    s += __shfl_xor(s, 1);   // butterfly: all 4 sublanes end up with the
    s += __shfl_xor(s, 2);   // full dot product
    int b = start[node], en = end[node];
    if (b < 0 || en > E || b >= en) return;  // poisoned run: node has no edges
    float tv = 2.0f * s / ((float)(en - b + 1) + 1e-16f);
    if (sub == 0) t[node] = tv;
    int S = pS[0];
    for (int e = b + sub; e < en; e += 4) {
        int j = e - S; if (j < 0) j += E;
        if (j < N) lk[j] = tv / ed[e];
    }
}

// out[k] = lk[row[orig(k)]] - lk[col[orig(k)]],  orig(k) = (k+S) mod E; tail zeros.
__global__ void k_out(const int* __restrict__ ei, const int* __restrict__ pS,
                      const float* __restrict__ lk, float* __restrict__ out,
                      int E, int N) {
    int k = blockIdx.x * blockDim.x + threadIdx.x;
    if (k < E) {
        int S = pS[0];
        int orig = k + S; if (orig >= E) orig -= E;
        int r, c;
        if (probe_stride(ei) == 2) {            // uniform branch
            int2 rc = ((const int2*)ei)[orig];  // one 8B load
            r = rc.x; c = rc.y;
        } else {
            int4 rc = ((const int4*)ei)[orig];  // one 16B load (int64 pairs)
            r = rc.x; c = rc.z;
        }
        out[k] = lk[r] - lk[c];
    } else if (k < E + N) {
        out[k] = 0.0f;
    }
}

extern "C" void kernel_launch(void* const* d_in, const int* in_sizes, int n_in,
                              void* d_out, int out_size, void* d_ws, size_t ws_size,
                              hipStream_t stream) {
    const float* x  = (const float*)d_in[0];
    const int*   ei = (const int*)d_in[1];
    const float* ed = (const float*)d_in[2];
    const float* W  = (const float*)d_in[3];
    // d_in[4] (attention) cancels out of the math entirely (softmax of equal
    // logits within every segment) and does not affect the output.
    float* out = (float*)d_out;

    int N = in_sizes[0] / C_IN;   // 65536
    int E = in_sizes[2];          // 1048576

    char* ws = (char*)d_ws;
    int*   start = (int*)ws;                           // N ints
    int*   end   = start + N;                          // N ints
    float* t     = (float*)(ws + (size_t)N * 8);       // N floats
    float* lk    = (float*)(ws + (size_t)N * 12);      // N floats
    float* w_sum = (float*)(ws + (size_t)N * 16);      // 128 floats
    int*   pS    = (int*)(ws + (size_t)N * 16 + 512);  // 1 int

    k_bound<<<(E + 255) / 256, 256, 0, stream>>>(ei, W, w_sum, start, end, pS, E);
    k_t<<<(N * 4 + 255) / 256, 256, 0, stream>>>(x, w_sum, start, end, ed, pS, t, lk, N, E);
    k_out<<<(E + N + 255) / 256, 256, 0, stream>>>(ei, pS, lk, out, E, N);
}